// Round 1
// baseline (1427.008 us; speedup 1.0000x reference)
//
#include <hip/hip_runtime.h>
#include <hip/hip_bf16.h>

constexpr float ALPHA_C = 3.0f;

constexpr int B_ = 2, M_ = 5, C_ = 64, H_ = 128, W_ = 256;
constexpr int BM_ = B_ * M_;              // 10
constexpr int HW_ = H_ * W_;              // 32768
constexpr int PLANE_ = C_ * HW_;          // 2,097,152
constexpr int NELEM_ = BM_ * PLANE_;      // 20,971,520

// conv tiling: 256 threads, 16x64 pixel tile, 8 output channels/block, 4 px/thread
constexpr int TH_ = 16, TW_ = 64, OCB_ = 8, PPT_ = 4;

typedef float f4v __attribute__((ext_vector_type(4)));

// ---------------- dtype sniffer ----------------
// pts ~ N(0,1). If buffer is bf16: every u16 is a bf16 with exponent ~[117,129].
// If fp32: u16 at even index is a low mantissa half (uniform) -> rarely in range.
__global__ void sniff_kernel(const unsigned short* __restrict__ pts,
                             int* __restrict__ flag) {
  int lane = threadIdx.x;  // block = 64 (one wave)
  unsigned short v = pts[2 * lane];
  int e = (v >> 7) & 0xFF;
  unsigned long long mask = __ballot(e >= 100 && e <= 140);
  if (lane == 0) flag[0] = (__popcll(mask) >= 48) ? 1 : 0;
}

template<bool BF16>
__device__ inline float ldIn(const void* p, int idx) {
  if constexpr (BF16)
    return __bfloat162float(((const __hip_bfloat16*)p)[idx]);
  else
    return ((const float*)p)[idx];
}

template<typename T> __device__ inline T toStore(float x);
template<> __device__ inline float toStore<float>(float x) { return x; }
template<> __device__ inline __hip_bfloat16 toStore<__hip_bfloat16>(float x) {
  return __float2bfloat16(x);
}

__device__ inline float fromStore(float x) { return x; }
__device__ inline float fromStore(__hip_bfloat16 x) { return __bfloat162float(x); }

// ---------------- conv3x3 + bias + tanh(3x) ----------------
template<bool BF16, typename StoreT>
__device__ void conv_body(const void* __restrict__ in,
                          const void* __restrict__ Wt,
                          const void* __restrict__ bias,
                          StoreT* __restrict__ out,
                          float* __restrict__ sW,    // [OCB_*C_*12]
                          float* __restrict__ sIn) { // [(TH_+2)*(TW_+2)]
  const int t = threadIdx.x;
  const int tx = blockIdx.x & 3;        // W tiles: 256/64 = 4
  const int ty = blockIdx.x >> 2;       // H tiles: 128/16 = 8
  const int ocg = blockIdx.y;           // 0..7
  const int img = blockIdx.z;           // 0..9
  const int oh0 = ty * TH_, ow0 = tx * TW_;

  // stage weights for this oc-group once: W[ocg*8+oc][ic][ky][kx] -> sW[(oc*C+ic)*12 + k]
  for (int i = t; i < OCB_ * C_ * 9; i += 256) {
    int k = i % 9;
    int ic = (i / 9) % C_;
    int oc = i / (9 * C_);
    sW[(oc * C_ + ic) * 12 + k] =
        ldIn<BF16>(Wt, ((ocg * OCB_ + oc) * C_ + ic) * 9 + k);
  }

  float acc[OCB_][PPT_];
#pragma unroll
  for (int oc = 0; oc < OCB_; ++oc)
#pragma unroll
    for (int p = 0; p < PPT_; ++p) acc[oc][p] = 0.f;

  const int lr = t >> 4;               // 0..15
  const int lcb = (t & 15) * PPT_;     // 0..60

  for (int ic = 0; ic < C_; ++ic) {
    __syncthreads();  // protect sIn from previous iteration (also covers sW on ic=0)
    const int base = img * PLANE_ + ic * HW_;
    for (int i = t; i < (TH_ + 2) * (TW_ + 2); i += 256) {
      int r = i / (TW_ + 2);
      int c = i - r * (TW_ + 2);
      int ih = oh0 - 1 + r, iw = ow0 - 1 + c;
      float v = 0.f;
      if ((unsigned)ih < (unsigned)H_ && (unsigned)iw < (unsigned)W_)
        v = ldIn<BF16>(in, base + ih * W_ + iw);
      sIn[r * (TW_ + 2) + c] = v;
    }
    __syncthreads();

    float v[3][PPT_ + 2];
#pragma unroll
    for (int r = 0; r < 3; ++r)
#pragma unroll
      for (int c = 0; c < PPT_ + 2; ++c)
        v[r][c] = sIn[(lr + r) * (TW_ + 2) + lcb + c];

#pragma unroll
    for (int oc = 0; oc < OCB_; ++oc) {
      const float* wp = &sW[(oc * C_ + ic) * 12];
      f4v w0 = *(const f4v*)wp;
      f4v w1 = *(const f4v*)(wp + 4);
      float w8 = wp[8];
#pragma unroll
      for (int p = 0; p < PPT_; ++p) {
        acc[oc][p] += w0.x * v[0][p]     + w0.y * v[0][p + 1] + w0.z * v[0][p + 2]
                    + w0.w * v[1][p]     + w1.x * v[1][p + 1] + w1.y * v[1][p + 2]
                    + w1.z * v[2][p]     + w1.w * v[2][p + 1] + w8   * v[2][p + 2];
      }
    }
  }

#pragma unroll
  for (int oc = 0; oc < OCB_; ++oc) {
    float bv = ldIn<BF16>(bias, ocg * OCB_ + oc);
    int o = img * PLANE_ + (ocg * OCB_ + oc) * HW_ + (oh0 + lr) * W_ + ow0 + lcb;
#pragma unroll
    for (int p = 0; p < PPT_; ++p)
      out[o + p] = toStore<StoreT>(tanhf(ALPHA_C * (acc[oc][p] + bv)));
  }
}

template<typename StoreT>
__global__ __launch_bounds__(256)
void conv_tanh_kernel(const void* __restrict__ in,
                      const void* __restrict__ Wt,
                      const void* __restrict__ bias,
                      StoreT* __restrict__ out,
                      const int* __restrict__ flag) {
  __shared__ float sW[OCB_ * C_ * 12];          // 24 KB
  __shared__ float sIn[(TH_ + 2) * (TW_ + 2)];  // 4.75 KB
  if (flag[0]) conv_body<true, StoreT>(in, Wt, bias, out, sW, sIn);
  else         conv_body<false, StoreT>(in, Wt, bias, out, sW, sIn);
}

// ---------------- pairwise gram + antisym + sigmoid + eye + row-normalize ----------------
template<typename StoreT>
__global__ __launch_bounds__(256)
void pairwise_kernel(const StoreT* __restrict__ n1,
                     const StoreT* __restrict__ n2,
                     void* __restrict__ out,
                     const int* __restrict__ flag) {
  int idx = blockIdx.x * 256 + threadIdx.x;  // 0 .. B*HW-1 (65536)
  int b = idx / HW_;
  int px = idx - b * HW_;
  const StoreT* p1 = n1 + b * (M_ * C_ * HW_) + px;
  const StoreT* p2 = n2 + b * (M_ * C_ * HW_) + px;

  float s[M_][M_];
#pragma unroll
  for (int m = 0; m < M_; ++m)
#pragma unroll
    for (int n = 0; n < M_; ++n) s[m][n] = 0.f;

  for (int l = 0; l < C_; ++l) {
    float a1[M_], a2[M_];
#pragma unroll
    for (int m = 0; m < M_; ++m) {
      a1[m] = fromStore(p1[(m * C_ + l) * HW_]);
      a2[m] = fromStore(p2[(m * C_ + l) * HW_]);
    }
#pragma unroll
    for (int m = 0; m < M_; ++m)
#pragma unroll
      for (int n = 0; n < M_; ++n) s[m][n] += a1[m] * a2[n];
  }

  float adj[M_][M_], rs[M_];
#pragma unroll
  for (int m = 0; m < M_; ++m) {
    float r = 0.f;
#pragma unroll
    for (int n = 0; n < M_; ++n) {
      float a = s[m][n] - s[n][m];
      float e = 1.f / (1.f + expf(-ALPHA_C * a));
      if (m == n) e += 1.f;
      adj[m][n] = e;
      r += e;
    }
    rs[m] = r;
  }

  const bool isb = (flag[0] != 0);
#pragma unroll
  for (int m = 0; m < M_; ++m) {
    float inv = 1.f / rs[m];
#pragma unroll
    for (int n = 0; n < M_; ++n) {
      float v = adj[m][n] * inv;
      int o = ((b * M_ + m) * M_ + n) * HW_ + px;
      if (isb) ((__hip_bfloat16*)out)[o] = __float2bfloat16(v);
      else     ((float*)out)[o] = v;
    }
  }
}

// ---------------- launch ----------------
extern "C" void kernel_launch(void* const* d_in, const int* in_sizes, int n_in,
                              void* d_out, int out_size, void* d_ws, size_t ws_size,
                              hipStream_t stream) {
  const void* pts = d_in[0];
  const void* W1  = d_in[1];
  const void* b1  = d_in[2];
  const void* W2  = d_in[3];
  const void* b2  = d_in[4];

  int* flag = (int*)d_ws;
  char* wsbase = (char*)d_ws + 256;

  sniff_kernel<<<dim3(1), dim3(64), 0, stream>>>((const unsigned short*)pts, flag);

  dim3 cgrid(32, C_ / OCB_, BM_);  // (8*4 tiles, 8 oc-groups, 10 images)
  dim3 blk(256);
  dim3 pgrid((B_ * HW_) / 256);    // 256 blocks

  size_t need_f32 = 256 + 2ull * NELEM_ * sizeof(float);  // ~168 MB
  if (ws_size >= need_f32) {
    float* n1 = (float*)wsbase;
    float* n2 = n1 + NELEM_;
    conv_tanh_kernel<float><<<cgrid, blk, 0, stream>>>(pts, W1, b1, n1, flag);
    conv_tanh_kernel<float><<<cgrid, blk, 0, stream>>>(pts, W2, b2, n2, flag);
    pairwise_kernel<float><<<pgrid, blk, 0, stream>>>(n1, n2, d_out, flag);
  } else {
    __hip_bfloat16* n1 = (__hip_bfloat16*)wsbase;
    __hip_bfloat16* n2 = n1 + NELEM_;
    conv_tanh_kernel<__hip_bfloat16><<<cgrid, blk, 0, stream>>>(pts, W1, b1, n1, flag);
    conv_tanh_kernel<__hip_bfloat16><<<cgrid, blk, 0, stream>>>(pts, W2, b2, n2, flag);
    pairwise_kernel<__hip_bfloat16><<<pgrid, blk, 0, stream>>>(n1, n2, d_out, flag);
  }
}

// Round 2
// 283.069 us; speedup vs baseline: 5.0412x; 5.0412x over previous
//
#include <hip/hip_runtime.h>
#include <hip/hip_bf16.h>

typedef _Float16 f16x8 __attribute__((ext_vector_type(8)));
typedef float f32x4 __attribute__((ext_vector_type(4)));

constexpr int B_ = 2, M_ = 5, C_ = 64, H_ = 128, W_ = 256;
constexpr int HW_ = H_ * W_;               // 32768
constexpr int PLANE_ = C_ * HW_;           // 2097152
constexpr int NIMG_ = B_ * M_;             // 10
constexpr int PH_ = H_ + 2, PW_ = W_ + 2;  // 130, 258

// workspace layout (bytes)
constexpr size_t OFF_XIN = 256;
constexpr size_t SZ_XIN  = (size_t)NIMG_ * PH_ * PW_ * 64 * 2;  // 42,931,200
constexpr size_t OFF_WL1 = OFF_XIN + SZ_XIN;
constexpr size_t SZ_WL   = (size_t)9 * 64 * 64 * 2;             // 73,728
constexpr size_t OFF_WL2 = OFF_WL1 + SZ_WL;
constexpr size_t OFF_N1  = OFF_WL2 + SZ_WL;
constexpr size_t SZ_N    = (size_t)NIMG_ * HW_ * 64 * 2;        // 41,943,040
constexpr size_t OFF_N2  = OFF_N1 + SZ_N;

// ---------------- dtype sniffer (unchanged from passing round) ----------------
__global__ void sniff_kernel(const unsigned short* __restrict__ pts,
                             int* __restrict__ flag) {
  int lane = threadIdx.x;  // block = 64
  unsigned short v = pts[2 * lane];
  int e = (v >> 7) & 0xFF;
  unsigned long long mask = __ballot(e >= 100 && e <= 140);
  if (lane == 0) flag[0] = (__popcll(mask) >= 48) ? 1 : 0;
}

// ---------------- zero the 1-px border of the padded NHWC buffer --------------
__global__ void border_zero(_Float16* __restrict__ x) {
  int idx = blockIdx.x * 256 + threadIdx.x;  // 10 * 772 = 7720 border pixels
  if (idx >= NIMG_ * 772) return;
  int img = idx / 772, r = idx - img * 772;
  int ph, pw;
  if (r < 258)      { ph = 0;            pw = r; }
  else if (r < 516) { ph = PH_ - 1;      pw = r - 258; }
  else if (r < 644) { ph = r - 516 + 1;  pw = 0; }
  else              { ph = r - 644 + 1;  pw = PW_ - 1; }
  f16x8 z = {};
  _Float16* p = x + ((size_t)(img * PH_ + ph) * PW_ + pw) * 64;
#pragma unroll
  for (int c8 = 0; c8 < 8; ++c8) *(f16x8*)(p + c8 * 8) = z;
}

// ---------------- NCHW (fp32|bf16) -> padded swizzled NHWC fp16 ---------------
__global__ __launch_bounds__(256) void prep_kernel(const void* __restrict__ in,
                                                   _Float16* __restrict__ xin,
                                                   const int* __restrict__ flag) {
  __shared__ float sT[64 * 65];
  const int t = threadIdx.x;
  const int wt = blockIdx.x, h = blockIdx.y, img = blockIdx.z;
  const bool isb = flag[0] != 0;
  const size_t ibase = (size_t)img * PLANE_ + (size_t)h * W_ + wt * 64;
#pragma unroll
  for (int k = 0; k < 16; ++k) {
    int idx = k * 256 + t;
    int ic = idx >> 6, w = idx & 63;
    size_t g = ibase + (size_t)ic * HW_ + w;
    float v = isb ? __bfloat162float(((const __hip_bfloat16*)in)[g])
                  : ((const float*)in)[g];
    sT[ic * 65 + w] = v;
  }
  __syncthreads();
#pragma unroll
  for (int k = 0; k < 2; ++k) {
    int idx = k * 256 + t;
    int w = idx >> 3, c8 = idx & 7;
    f16x8 vv;
#pragma unroll
    for (int j = 0; j < 8; ++j) vv[j] = (_Float16)sT[(c8 * 8 + j) * 65 + w];
    int pw = wt * 64 + w + 1;
    size_t rowbase = ((size_t)(img * PH_ + (h + 1)) * PW_ + pw) * 128;  // bytes
    int off = (c8 * 16) ^ ((pw & 7) << 4);
    *(f16x8*)((char*)xin + rowbase + off) = vv;
  }
}

// ---------------- W [oc][ic][3][3] -> swizzled fp16 [tap][oc][ic] -------------
__global__ void wprep_kernel(const void* __restrict__ W1, const void* __restrict__ W2,
                             _Float16* __restrict__ wl1, _Float16* __restrict__ wl2,
                             const int* __restrict__ flag) {
  int idx = blockIdx.x * 256 + threadIdx.x;  // 0..36863, grid.y selects matrix
  const bool isb = flag[0] != 0;
  const void* Wsrc = blockIdx.y ? W2 : W1;
  _Float16* dst = blockIdx.y ? wl2 : wl1;
  int tap = idx >> 12;            // /4096
  int oc = (idx >> 6) & 63;
  int ic = idx & 63;
  size_t s = (size_t)(oc * 64 + ic) * 9 + tap;
  float v = isb ? __bfloat162float(((const __hip_bfloat16*)Wsrc)[s])
                : ((const float*)Wsrc)[s];
  dst[(tap * 4096 + oc * 64 + ic) ^ ((oc & 7) << 3)] = (_Float16)v;
}

// ---------------- conv3x3 + bias + tanh(3x) via MFMA --------------------------
// output tile: 4 rows x 64 cols x 64 oc per block (4 waves, 1 row each)
__global__ __launch_bounds__(256, 1)
void conv_mfma(const _Float16* __restrict__ xin, const _Float16* __restrict__ wl,
               const void* __restrict__ bias, const int* __restrict__ flag,
               _Float16* __restrict__ out) {
  __shared__ _Float16 sIn[6 * 66 * 64];  // 50,688 B, swizzled rows of 66 px
  __shared__ _Float16 sW[9 * 64 * 64];   // 73,728 B, swizzled [tap][oc][ic]

  const int t = threadIdx.x;
  const int w0 = blockIdx.x * 64;   // 0,64,128,192 (true col of first output)
  const int h0 = blockIdx.y * 4;    // 0..124
  const int img = blockIdx.z;

  // --- stage: linear byte-copies preserve the pre-applied swizzle ---
#pragma unroll
  for (int r = 0; r < 6; ++r) {
    const f16x8* src = (const f16x8*)(xin + ((size_t)(img * PH_ + h0 + r) * PW_ + w0) * 64);
    f16x8* dst = (f16x8*)(sIn + r * 4224);
    for (int i = t; i < 528; i += 256) dst[i] = src[i];
  }
  {
    const f16x8* src = (const f16x8*)wl;
    f16x8* dst = (f16x8*)sW;
    for (int i = t; i < 4608; i += 256) dst[i] = src[i];
  }
  __syncthreads();

  const int l = t & 63, wv = t >> 6;
  const int lr = l & 15, hi = l >> 4;

  // swizzled channel-offset terms (bits 4-6 are XORed, so precompute per dx/kw)
  int c2a[3][2], c2b[2];
#pragma unroll
  for (int dx = 0; dx < 3; ++dx) {
    int key = (((l & 7) + dx) & 7) << 4;
#pragma unroll
    for (int kw = 0; kw < 2; ++kw) c2a[dx][kw] = (hi * 16 + kw * 64) ^ key;
  }
#pragma unroll
  for (int kw = 0; kw < 2; ++kw) c2b[kw] = (hi * 16 + kw * 64) ^ ((l & 7) << 4);

  f32x4 acc[4][4];
#pragma unroll
  for (int pa = 0; pa < 4; ++pa)
#pragma unroll
    for (int ob = 0; ob < 4; ++ob) acc[pa][ob] = (f32x4){0.f, 0.f, 0.f, 0.f};

  const char* sInB = (const char*)sIn;
  const char* sWB = (const char*)sW;

#pragma unroll
  for (int ky = 0; ky < 3; ++ky) {
#pragma unroll
    for (int kx = 0; kx < 3; ++kx) {
      const int tap = ky * 3 + kx;
#pragma unroll
      for (int kw = 0; kw < 2; ++kw) {
        f16x8 a[4], b[4];
#pragma unroll
        for (int pa = 0; pa < 4; ++pa)
          a[pa] = *(const f16x8*)(sInB + ((wv + ky) * 8448 + (pa * 16 + lr + kx) * 128 + c2a[kx][kw]));
#pragma unroll
        for (int ob = 0; ob < 4; ++ob)
          b[ob] = *(const f16x8*)(sWB + (tap * 8192 + (ob * 16 + lr) * 128 + c2b[kw]));
#pragma unroll
        for (int pa = 0; pa < 4; ++pa)
#pragma unroll
          for (int ob = 0; ob < 4; ++ob)
            acc[pa][ob] = __builtin_amdgcn_mfma_f32_16x16x32_f16(a[pa], b[ob], acc[pa][ob], 0, 0, 0);
      }
    }
  }

  __syncthreads();  // everyone done reading sW before we reuse it for repack

  const bool isb = flag[0] != 0;
  float bv[4];
#pragma unroll
  for (int ob = 0; ob < 4; ++ob) {
    int oc = ob * 16 + lr;
    bv[ob] = isb ? __bfloat162float(((const __hip_bfloat16*)bias)[oc])
                 : ((const float*)bias)[oc];
  }

  _Float16* st = sW + wv * 8192;  // per-wave 16 KB repack region
#pragma unroll
  for (int pa = 0; pa < 4; ++pa)
#pragma unroll
    for (int ob = 0; ob < 4; ++ob)
#pragma unroll
      for (int r = 0; r < 4; ++r) {
        int px = pa * 16 + hi * 4 + r;
        int oc = ob * 16 + lr;
        float u = acc[pa][ob][r] + bv[ob];
        u = fminf(fmaxf(u, -8.f), 8.f);
        float e = __builtin_exp2f(u * -8.656170245f);  // exp(-6u)
        float v = (1.f - e) * __builtin_amdgcn_rcpf(1.f + e);
        int byteoff = (px * 128 + oc * 2) ^ ((px & 7) << 4);
        *(_Float16*)((char*)st + byteoff) = (_Float16)v;
      }

  // linear read-back -> coalesced global store (per-px ch-permutation kept,
  // consistent across both convs; Gram sum is permutation-invariant)
  _Float16* gout = out + (((size_t)img * H_ + (h0 + wv)) * W_ + w0) * 64;
#pragma unroll
  for (int j = 0; j < 8; ++j) {
    int chunk = j * 64 + l;
    f16x8 vv = *(const f16x8*)((const char*)st + chunk * 16);
    *(f16x8*)(gout + (size_t)chunk * 8) = vv;
  }
}

// ---------------- gram + antisym + sigmoid + eye + row-normalize --------------
__global__ __launch_bounds__(256)
void pairwise_kernel(const _Float16* __restrict__ n1, const _Float16* __restrict__ n2,
                     void* __restrict__ out, const int* __restrict__ flag) {
  int idx = blockIdx.x * 256 + threadIdx.x;  // 0 .. B*HW-1
  int b = idx >> 15, px = idx & (HW_ - 1);
  const _Float16* p1 = n1 + ((size_t)(b * M_) * HW_ + px) * 64;
  const _Float16* p2 = n2 + ((size_t)(b * M_) * HW_ + px) * 64;

  float s[M_][M_];
#pragma unroll
  for (int m = 0; m < M_; ++m)
#pragma unroll
    for (int n = 0; n < M_; ++n) s[m][n] = 0.f;

#pragma unroll
  for (int c8 = 0; c8 < 8; ++c8) {
    f16x8 A[M_], Bv[M_];
#pragma unroll
    for (int m = 0; m < M_; ++m) {
      A[m]  = *(const f16x8*)(p1 + (size_t)m * PLANE_ + c8 * 8);
      Bv[m] = *(const f16x8*)(p2 + (size_t)m * PLANE_ + c8 * 8);
    }
#pragma unroll
    for (int j = 0; j < 8; ++j)
#pragma unroll
      for (int m = 0; m < M_; ++m)
#pragma unroll
        for (int n = 0; n < M_; ++n)
          s[m][n] += (float)A[m][j] * (float)Bv[n][j];
  }

  float adj[M_][M_], rs[M_];
#pragma unroll
  for (int m = 0; m < M_; ++m) {
    float r = 0.f;
#pragma unroll
    for (int n = 0; n < M_; ++n) {
      float a = s[m][n] - s[n][m];
      float e = __builtin_exp2f(a * -4.328085123f);  // exp(-3a)
      float v = __builtin_amdgcn_rcpf(1.f + e);
      if (m == n) v += 1.f;
      adj[m][n] = v;
      r += v;
    }
    rs[m] = r;
  }

  const bool isb = flag[0] != 0;
#pragma unroll
  for (int m = 0; m < M_; ++m) {
    float inv = __builtin_amdgcn_rcpf(rs[m]);
#pragma unroll
    for (int n = 0; n < M_; ++n) {
      float v = adj[m][n] * inv;
      size_t o = ((size_t)((b * M_ + m) * M_ + n)) * HW_ + px;
      if (isb) ((__hip_bfloat16*)out)[o] = __float2bfloat16(v);
      else     ((float*)out)[o] = v;
    }
  }
}

// ---------------- launch ----------------
extern "C" void kernel_launch(void* const* d_in, const int* in_sizes, int n_in,
                              void* d_out, int out_size, void* d_ws, size_t ws_size,
                              hipStream_t stream) {
  const void* pts = d_in[0];
  const void* W1  = d_in[1];
  const void* b1  = d_in[2];
  const void* W2  = d_in[3];
  const void* b2  = d_in[4];

  char* ws = (char*)d_ws;
  int* flag = (int*)ws;
  _Float16* xin = (_Float16*)(ws + OFF_XIN);
  _Float16* wl1 = (_Float16*)(ws + OFF_WL1);
  _Float16* wl2 = (_Float16*)(ws + OFF_WL2);
  _Float16* n1  = (_Float16*)(ws + OFF_N1);
  _Float16* n2  = (_Float16*)(ws + OFF_N2);

  sniff_kernel<<<dim3(1), dim3(64), 0, stream>>>((const unsigned short*)pts, flag);
  border_zero<<<dim3((NIMG_ * 772 + 255) / 256), dim3(256), 0, stream>>>(xin);
  prep_kernel<<<dim3(4, H_, NIMG_), dim3(256), 0, stream>>>(pts, xin, flag);
  wprep_kernel<<<dim3(144, 2), dim3(256), 0, stream>>>(W1, W2, wl1, wl2, flag);
  conv_mfma<<<dim3(4, 32, NIMG_), dim3(256), 0, stream>>>(xin, wl1, b1, flag, n1);
  conv_mfma<<<dim3(4, 32, NIMG_), dim3(256), 0, stream>>>(xin, wl2, b2, flag, n2);
  pairwise_kernel<<<dim3(B_ * HW_ / 256), dim3(256), 0, stream>>>(n1, n2, d_out, flag);
}

// Round 3
// 177.670 us; speedup vs baseline: 8.0318x; 1.5932x over previous
//
#include <hip/hip_runtime.h>
#include <hip/hip_bf16.h>

typedef _Float16 f16x8 __attribute__((ext_vector_type(8)));
typedef float f32x4 __attribute__((ext_vector_type(4)));

constexpr int B_ = 2, M_ = 5, C_ = 64, H_ = 128, W_ = 256;
constexpr int HW_ = H_ * W_;               // 32768
constexpr int PLANE_ = C_ * HW_;           // 2097152
constexpr int NIMG_ = B_ * M_;             // 10
constexpr int PH_ = H_ + 2, PW_ = W_ + 2;  // 130, 258

// workspace layout (bytes)
constexpr size_t OFF_XIN = 256;
constexpr size_t SZ_XIN  = (size_t)NIMG_ * PH_ * PW_ * 64 * 2;  // 42,931,200
constexpr size_t OFF_WL1 = OFF_XIN + SZ_XIN;
constexpr size_t SZ_WL   = (size_t)9 * 64 * 64 * 2;             // 73,728
constexpr size_t OFF_WL2 = OFF_WL1 + SZ_WL;
constexpr size_t OFF_N1  = OFF_WL2 + SZ_WL;
constexpr size_t SZ_N    = (size_t)NIMG_ * HW_ * 64 * 2;        // 41,943,040
constexpr size_t OFF_N2  = OFF_N1 + SZ_N;

// ---------------- dtype sniffer ----------------
__global__ void sniff_kernel(const unsigned short* __restrict__ pts,
                             int* __restrict__ flag) {
  int lane = threadIdx.x;  // block = 64
  unsigned short v = pts[2 * lane];
  int e = (v >> 7) & 0xFF;
  unsigned long long mask = __ballot(e >= 100 && e <= 140);
  if (lane == 0) flag[0] = (__popcll(mask) >= 48) ? 1 : 0;
}

// ---------------- zero the 1-px border of the padded NHWC buffer --------------
__global__ void border_zero(_Float16* __restrict__ x) {
  int idx = blockIdx.x * 256 + threadIdx.x;  // 10 * 772 = 7720 border pixels
  if (idx >= NIMG_ * 772) return;
  int img = idx / 772, r = idx - img * 772;
  int ph, pw;
  if (r < 258)      { ph = 0;            pw = r; }
  else if (r < 516) { ph = PH_ - 1;      pw = r - 258; }
  else if (r < 644) { ph = r - 516 + 1;  pw = 0; }
  else              { ph = r - 644 + 1;  pw = PW_ - 1; }
  f16x8 z = {};
  _Float16* p = x + ((size_t)(img * PH_ + ph) * PW_ + pw) * 64;
#pragma unroll
  for (int c8 = 0; c8 < 8; ++c8) *(f16x8*)(p + c8 * 8) = z;
}

// ---------------- NCHW (fp32|bf16) -> padded swizzled NHWC fp16 ---------------
__global__ __launch_bounds__(256) void prep_kernel(const void* __restrict__ in,
                                                   _Float16* __restrict__ xin,
                                                   const int* __restrict__ flag) {
  __shared__ float sT[64 * 65];
  const int t = threadIdx.x;
  const int wt = blockIdx.x, h = blockIdx.y, img = blockIdx.z;
  const bool isb = flag[0] != 0;
  const size_t ibase = (size_t)img * PLANE_ + (size_t)h * W_ + wt * 64;
#pragma unroll
  for (int k = 0; k < 16; ++k) {
    int idx = k * 256 + t;
    int ic = idx >> 6, w = idx & 63;
    size_t g = ibase + (size_t)ic * HW_ + w;
    float v = isb ? __bfloat162float(((const __hip_bfloat16*)in)[g])
                  : ((const float*)in)[g];
    sT[ic * 65 + w] = v;
  }
  __syncthreads();
#pragma unroll
  for (int k = 0; k < 2; ++k) {
    int idx = k * 256 + t;
    int w = idx >> 3, c8 = idx & 7;
    f16x8 vv;
#pragma unroll
    for (int j = 0; j < 8; ++j) vv[j] = (_Float16)sT[(c8 * 8 + j) * 65 + w];
    int pw = wt * 64 + w + 1;
    size_t rowbase = ((size_t)(img * PH_ + (h + 1)) * PW_ + pw) * 128;  // bytes
    int off = (c8 * 16) ^ ((pw & 7) << 4);
    *(f16x8*)((char*)xin + rowbase + off) = vv;
  }
}

// ---------------- W [oc][ic][3][3] -> swizzled fp16 [tap][oc][ic] -------------
__global__ void wprep_kernel(const void* __restrict__ W1, const void* __restrict__ W2,
                             _Float16* __restrict__ wl1, _Float16* __restrict__ wl2,
                             const int* __restrict__ flag) {
  int idx = blockIdx.x * 256 + threadIdx.x;  // 0..36863, grid.y selects matrix
  const bool isb = flag[0] != 0;
  const void* Wsrc = blockIdx.y ? W2 : W1;
  _Float16* dst = blockIdx.y ? wl2 : wl1;
  int tap = idx >> 12;            // /4096
  int oc = (idx >> 6) & 63;
  int ic = idx & 63;
  size_t s = (size_t)(oc * 64 + ic) * 9 + tap;
  float v = isb ? __bfloat162float(((const __hip_bfloat16*)Wsrc)[s])
                : ((const float*)Wsrc)[s];
  dst[(tap * 4096 + oc * 64 + ic) ^ ((oc & 7) << 3)] = (_Float16)v;
}

// ---------------- conv3x3 + bias + tanh(3x) via MFMA --------------------------
// output tile: 8 rows x 64 cols x 64 oc per block (8 waves, 1 row each)
__global__ __launch_bounds__(512, 1)
void conv_mfma(const _Float16* __restrict__ xin, const _Float16* __restrict__ wl,
               const void* __restrict__ bias, const int* __restrict__ flag,
               _Float16* __restrict__ out) {
  __shared__ _Float16 sIn[10 * 66 * 64];  // 84,480 B, swizzled rows of 66 px
  __shared__ _Float16 sW[9 * 64 * 64];    // 73,728 B, swizzled [tap][oc][ic]

  const int t = threadIdx.x;
  const int w0 = blockIdx.x * 64;   // 0,64,128,192 (true col of first output)
  const int h0 = blockIdx.y * 8;    // 0..120
  const int img = blockIdx.z;

  // --- stage: linear byte-copies preserve the pre-applied swizzle ---
#pragma unroll
  for (int r = 0; r < 10; ++r) {
    const f16x8* src = (const f16x8*)(xin + ((size_t)(img * PH_ + h0 + r) * PW_ + w0) * 64);
    f16x8* dst = (f16x8*)(sIn + r * 4224);
    for (int i = t; i < 528; i += 512) dst[i] = src[i];
  }
  {
    const f16x8* src = (const f16x8*)wl;
    f16x8* dst = (f16x8*)sW;
    for (int i = t; i < 4608; i += 512) dst[i] = src[i];
  }
  __syncthreads();

  const int l = t & 63, wv = t >> 6;   // wv 0..7
  const int lr = l & 15, hi = l >> 4;

  // swizzled channel-offset terms (bits 4-6 are XORed, so precompute per dx/kw)
  int c2a[3][2], c2b[2];
#pragma unroll
  for (int dx = 0; dx < 3; ++dx) {
    int key = (((l & 7) + dx) & 7) << 4;
#pragma unroll
    for (int kw = 0; kw < 2; ++kw) c2a[dx][kw] = (hi * 16 + kw * 64) ^ key;
  }
#pragma unroll
  for (int kw = 0; kw < 2; ++kw) c2b[kw] = (hi * 16 + kw * 64) ^ ((l & 7) << 4);

  f32x4 acc[4][4];
#pragma unroll
  for (int pa = 0; pa < 4; ++pa)
#pragma unroll
    for (int ob = 0; ob < 4; ++ob) acc[pa][ob] = (f32x4){0.f, 0.f, 0.f, 0.f};

  const char* sInB = (const char*)sIn;
  const char* sWB = (const char*)sW;

#pragma unroll
  for (int ky = 0; ky < 3; ++ky) {
#pragma unroll
    for (int kx = 0; kx < 3; ++kx) {
      const int tap = ky * 3 + kx;
#pragma unroll
      for (int kw = 0; kw < 2; ++kw) {
        f16x8 a[4], b[4];
#pragma unroll
        for (int pa = 0; pa < 4; ++pa)
          a[pa] = *(const f16x8*)(sInB + ((wv + ky) * 8448 + (pa * 16 + lr + kx) * 128 + c2a[kx][kw]));
#pragma unroll
        for (int ob = 0; ob < 4; ++ob)
          b[ob] = *(const f16x8*)(sWB + (tap * 8192 + (ob * 16 + lr) * 128 + c2b[kw]));
#pragma unroll
        for (int pa = 0; pa < 4; ++pa)
#pragma unroll
          for (int ob = 0; ob < 4; ++ob)
            acc[pa][ob] = __builtin_amdgcn_mfma_f32_16x16x32_f16(a[pa], b[ob], acc[pa][ob], 0, 0, 0);
      }
    }
  }

  __syncthreads();  // everyone done reading sW before we reuse it for repack

  const bool isb = flag[0] != 0;
  float bv[4];
#pragma unroll
  for (int ob = 0; ob < 4; ++ob) {
    int oc = ob * 16 + lr;
    bv[ob] = isb ? __bfloat162float(((const __hip_bfloat16*)bias)[oc])
                 : ((const float*)bias)[oc];
  }

  _Float16* st = sW + wv * 4096;  // per-wave 8 KB repack region (8 waves = 64 KB)
#pragma unroll
  for (int pa = 0; pa < 4; ++pa)
#pragma unroll
    for (int ob = 0; ob < 4; ++ob)
#pragma unroll
      for (int r = 0; r < 4; ++r) {
        int px = pa * 16 + hi * 4 + r;
        int oc = ob * 16 + lr;
        float u = acc[pa][ob][r] + bv[ob];
        u = fminf(fmaxf(u, -8.f), 8.f);
        float e = __builtin_exp2f(u * -8.656170245f);  // exp(-6u)
        float v = (1.f - e) * __builtin_amdgcn_rcpf(1.f + e);
        int byteoff = (px * 128 + oc * 2) ^ ((px & 7) << 4);
        *(_Float16*)((char*)st + byteoff) = (_Float16)v;
      }

  // linear read-back -> coalesced global store (per-px ch-permutation kept,
  // consistent across both convs; Gram sum is permutation-invariant)
  _Float16* gout = out + (((size_t)img * H_ + (h0 + wv)) * W_ + w0) * 64;
#pragma unroll
  for (int j = 0; j < 8; ++j) {
    int chunk = j * 64 + l;
    f16x8 vv = *(const f16x8*)((const char*)st + chunk * 16);
    *(f16x8*)(gout + (size_t)chunk * 8) = vv;
  }
}

// ---------------- gram + antisym + sigmoid + eye + row-normalize --------------
// 8 lanes cooperate per pixel: lane octet j owns channels 8j..8j+7.
// Wave reads 1024 contiguous bytes per load instruction (fully coalesced).
__global__ __launch_bounds__(256)
void pairwise_kernel(const _Float16* __restrict__ n1, const _Float16* __restrict__ n2,
                     void* __restrict__ out, const int* __restrict__ flag) {
  int tid = blockIdx.x * 256 + threadIdx.x;
  int gp = tid >> 3;               // pixel id 0 .. B*HW-1
  int j = tid & 7;                 // channel octet
  int b = gp >> 15, px = gp & (HW_ - 1);
  const _Float16* p1 = n1 + ((size_t)(b * M_) * HW_ + px) * 64 + j * 8;
  const _Float16* p2 = n2 + ((size_t)(b * M_) * HW_ + px) * 64 + j * 8;

  f16x8 A[M_], Bv[M_];
#pragma unroll
  for (int m = 0; m < M_; ++m) {
    A[m]  = *(const f16x8*)(p1 + (size_t)m * PLANE_);
    Bv[m] = *(const f16x8*)(p2 + (size_t)m * PLANE_);
  }

  float s[M_][M_];
#pragma unroll
  for (int m = 0; m < M_; ++m)
#pragma unroll
    for (int n = 0; n < M_; ++n) s[m][n] = 0.f;

#pragma unroll
  for (int jj = 0; jj < 8; ++jj)
#pragma unroll
    for (int m = 0; m < M_; ++m)
#pragma unroll
      for (int n = 0; n < M_; ++n)
        s[m][n] += (float)A[m][jj] * (float)Bv[n][jj];

  // allreduce the 25 partials across the 8-lane octet group
#pragma unroll
  for (int m = 0; m < M_; ++m)
#pragma unroll
    for (int n = 0; n < M_; ++n) {
      s[m][n] += __shfl_xor(s[m][n], 1);
      s[m][n] += __shfl_xor(s[m][n], 2);
      s[m][n] += __shfl_xor(s[m][n], 4);
    }

  float adj[M_][M_], rs[M_];
#pragma unroll
  for (int m = 0; m < M_; ++m) {
    float r = 0.f;
#pragma unroll
    for (int n = 0; n < M_; ++n) {
      float a = s[m][n] - s[n][m];
      float e = __builtin_exp2f(a * -4.328085123f);  // exp(-3a)
      float v = __builtin_amdgcn_rcpf(1.f + e);
      if (m == n) v += 1.f;
      adj[m][n] = v;
      r += v;
    }
    rs[m] = r;
  }

  const bool isb = flag[0] != 0;
  // lane j stores entries k = j, j+8, j+16, j+24(<25)
  for (int k = j; k < 25; k += 8) {
    int m = k / 5, n = k - m * 5;
    float v = adj[m][n] * __builtin_amdgcn_rcpf(rs[m]);
    size_t o = ((size_t)((b * M_ + m) * M_ + n)) * HW_ + px;
    if (isb) ((__hip_bfloat16*)out)[o] = __float2bfloat16(v);
    else     ((float*)out)[o] = v;
  }
}

// ---------------- launch ----------------
extern "C" void kernel_launch(void* const* d_in, const int* in_sizes, int n_in,
                              void* d_out, int out_size, void* d_ws, size_t ws_size,
                              hipStream_t stream) {
  const void* pts = d_in[0];
  const void* W1  = d_in[1];
  const void* b1  = d_in[2];
  const void* W2  = d_in[3];
  const void* b2  = d_in[4];

  char* ws = (char*)d_ws;
  int* flag = (int*)ws;
  _Float16* xin = (_Float16*)(ws + OFF_XIN);
  _Float16* wl1 = (_Float16*)(ws + OFF_WL1);
  _Float16* wl2 = (_Float16*)(ws + OFF_WL2);
  _Float16* n1  = (_Float16*)(ws + OFF_N1);
  _Float16* n2  = (_Float16*)(ws + OFF_N2);

  sniff_kernel<<<dim3(1), dim3(64), 0, stream>>>((const unsigned short*)pts, flag);
  border_zero<<<dim3((NIMG_ * 772 + 255) / 256), dim3(256), 0, stream>>>(xin);
  prep_kernel<<<dim3(4, H_, NIMG_), dim3(256), 0, stream>>>(pts, xin, flag);
  wprep_kernel<<<dim3(144, 2), dim3(256), 0, stream>>>(W1, W2, wl1, wl2, flag);
  conv_mfma<<<dim3(4, 16, NIMG_), dim3(512), 0, stream>>>(xin, wl1, b1, flag, n1);
  conv_mfma<<<dim3(4, 16, NIMG_), dim3(512), 0, stream>>>(xin, wl2, b2, flag, n2);
  pairwise_kernel<<<dim3(B_ * HW_ * 8 / 256), dim3(256), 0, stream>>>(n1, n2, d_out, flag);
}

// Round 4
// 134.739 us; speedup vs baseline: 10.5909x; 1.3186x over previous
//
#include <hip/hip_runtime.h>
#include <hip/hip_bf16.h>

typedef _Float16 f16x8 __attribute__((ext_vector_type(8)));
typedef float f32x4 __attribute__((ext_vector_type(4)));

constexpr int B_ = 2, M_ = 5, C_ = 64, H_ = 128, W_ = 256;
constexpr int HW_ = H_ * W_;               // 32768
constexpr int PLANE_ = C_ * HW_;           // 2097152
constexpr int NIMG_ = B_ * M_;             // 10
constexpr int PH_ = H_ + 2, PW_ = W_ + 2;  // 130, 258

// workspace layout (bytes)
constexpr size_t OFF_XIN = 256;
constexpr size_t SZ_XIN  = (size_t)NIMG_ * PH_ * PW_ * 64 * 2;  // 42,931,200
constexpr size_t OFF_WL1 = OFF_XIN + SZ_XIN;
constexpr size_t SZ_WL   = (size_t)9 * 64 * 64 * 2;             // 73,728
constexpr size_t OFF_WL2 = OFF_WL1 + SZ_WL;
constexpr size_t OFF_N1  = OFF_WL2 + SZ_WL;
constexpr size_t SZ_N    = (size_t)NIMG_ * HW_ * 64 * 2;        // 41,943,040
constexpr size_t OFF_N2  = OFF_N1 + SZ_N;

// ---------------- dtype sniffer ----------------
__global__ void sniff_kernel(const unsigned short* __restrict__ pts,
                             int* __restrict__ flag) {
  int lane = threadIdx.x;  // block = 64
  unsigned short v = pts[2 * lane];
  int e = (v >> 7) & 0xFF;
  unsigned long long mask = __ballot(e >= 100 && e <= 140);
  if (lane == 0) flag[0] = (__popcll(mask) >= 48) ? 1 : 0;
}

// ---------------- zero the 1-px border of the padded NHWC buffer --------------
__global__ void border_zero(_Float16* __restrict__ x) {
  int idx = blockIdx.x * 256 + threadIdx.x;  // 10 * 772 = 7720 border pixels
  if (idx >= NIMG_ * 772) return;
  int img = idx / 772, r = idx - img * 772;
  int ph, pw;
  if (r < 258)      { ph = 0;            pw = r; }
  else if (r < 516) { ph = PH_ - 1;      pw = r - 258; }
  else if (r < 644) { ph = r - 516 + 1;  pw = 0; }
  else              { ph = r - 644 + 1;  pw = PW_ - 1; }
  f16x8 z = {};
  _Float16* p = x + ((size_t)(img * PH_ + ph) * PW_ + pw) * 64;
#pragma unroll
  for (int c8 = 0; c8 < 8; ++c8) *(f16x8*)(p + c8 * 8) = z;
}

// ---------------- NCHW (fp32|bf16) -> padded swizzled NHWC fp16 ---------------
__global__ __launch_bounds__(256) void prep_kernel(const void* __restrict__ in,
                                                   _Float16* __restrict__ xin,
                                                   const int* __restrict__ flag) {
  __shared__ float sT[64 * 65];
  const int t = threadIdx.x;
  const int wt = blockIdx.x, h = blockIdx.y, img = blockIdx.z;
  const bool isb = flag[0] != 0;
  const size_t ibase = (size_t)img * PLANE_ + (size_t)h * W_ + wt * 64;
#pragma unroll
  for (int k = 0; k < 16; ++k) {
    int idx = k * 256 + t;
    int ic = idx >> 6, w = idx & 63;
    size_t g = ibase + (size_t)ic * HW_ + w;
    float v = isb ? __bfloat162float(((const __hip_bfloat16*)in)[g])
                  : ((const float*)in)[g];
    sT[ic * 65 + w] = v;
  }
  __syncthreads();
#pragma unroll
  for (int k = 0; k < 2; ++k) {
    int idx = k * 256 + t;
    int w = idx >> 3, c8 = idx & 7;
    f16x8 vv;
#pragma unroll
    for (int j = 0; j < 8; ++j) vv[j] = (_Float16)sT[(c8 * 8 + j) * 65 + w];
    int pw = wt * 64 + w + 1;
    size_t rowbase = ((size_t)(img * PH_ + (h + 1)) * PW_ + pw) * 128;  // bytes
    int off = (c8 * 16) ^ ((pw & 7) << 4);
    *(f16x8*)((char*)xin + rowbase + off) = vv;
  }
}

// ---------------- W [oc][ic][3][3] -> swizzled fp16 [tap][oc][ic] -------------
__global__ void wprep_kernel(const void* __restrict__ W1, const void* __restrict__ W2,
                             _Float16* __restrict__ wl1, _Float16* __restrict__ wl2,
                             const int* __restrict__ flag) {
  int idx = blockIdx.x * 256 + threadIdx.x;  // 0..36863, grid.y selects matrix
  const bool isb = flag[0] != 0;
  const void* Wsrc = blockIdx.y ? W2 : W1;
  _Float16* dst = blockIdx.y ? wl2 : wl1;
  int tap = idx >> 12;            // /4096
  int oc = (idx >> 6) & 63;
  int ic = idx & 63;
  size_t s = (size_t)(oc * 64 + ic) * 9 + tap;
  float v = isb ? __bfloat162float(((const __hip_bfloat16*)Wsrc)[s])
                : ((const float*)Wsrc)[s];
  dst[(tap * 4096 + oc * 64 + ic) ^ ((oc & 7) << 3)] = (_Float16)v;
}

// ---------------- persistent fused conv: both convs, oc-half per block --------
// grid = 256 blocks x 512 threads. Block k: oc-half (k&1), tile set (k>>1)+128j,
// j = 0..4. Weights staged once; input tiles pipelined via register staging.
__global__ __launch_bounds__(512, 2)
void conv_fused(const _Float16* __restrict__ xin,
                const _Float16* __restrict__ wl1, const _Float16* __restrict__ wl2,
                const void* __restrict__ bias1, const void* __restrict__ bias2,
                const int* __restrict__ flag,
                _Float16* __restrict__ n1, _Float16* __restrict__ n2) {
  __shared__ _Float16 sIn[10 * 66 * 64];    // 84,480 B, swizzled rows of 66 px
  __shared__ _Float16 sW[2 * 9 * 32 * 64];  // 73,728 B: [conv][tap][oc32][ic64]

  const int t = threadIdx.x;
  const int och = blockIdx.x & 1;
  const int pid = blockIdx.x >> 1;          // 0..127

  const int l = t & 63, wv = t >> 6;        // wv 0..7
  const int lr = l & 15, hi = l >> 4;
  const bool isb = flag[0] != 0;

  // --- stage weights once: conv c, tap, oc rows och*32..och*32+31 (contiguous,
  //     4 KB per tap; linear copy preserves the pre-applied swizzle) ---
#pragma unroll
  for (int c = 0; c < 2; ++c) {
    const f16x8* src = (const f16x8*)((const char*)(c ? wl2 : wl1) + och * 4096);
    f16x8* dst = (f16x8*)sW + c * 2304;
    for (int i = t; i < 2304; i += 512) {
      int tap = i >> 8, e = i & 255;
      dst[i] = src[tap * 512 + e];   // src tap stride = 8192 B = 512 f16x8
    }
  }

  float bv1[2], bv2[2];
#pragma unroll
  for (int ob = 0; ob < 2; ++ob) {
    int oc = och * 32 + ob * 16 + lr;
    bv1[ob] = isb ? __bfloat162float(((const __hip_bfloat16*)bias1)[oc])
                  : ((const float*)bias1)[oc];
    bv2[ob] = isb ? __bfloat162float(((const __hip_bfloat16*)bias2)[oc])
                  : ((const float*)bias2)[oc];
  }

  // swizzled channel-offset terms
  int c2a[3][2], c2b[2];
#pragma unroll
  for (int dx = 0; dx < 3; ++dx) {
    int key = (((l & 7) + dx) & 7) << 4;
#pragma unroll
    for (int kw = 0; kw < 2; ++kw) c2a[dx][kw] = (hi * 16 + kw * 64) ^ key;
  }
#pragma unroll
  for (int kw = 0; kw < 2; ++kw) c2b[kw] = (hi * 16 + kw * 64) ^ ((l & 7) << 4);

  // --- register staging: tile = 10 rows x 528 f16x8; 11 regs/thread ---
  f16x8 rg[11];
  auto issue = [&](int tt) {
    int img = tt >> 6, hy = (tt >> 2) & 15, wx = tt & 3;
    const f16x8* base = (const f16x8*)(xin + ((size_t)(img * PH_ + hy * 8) * PW_ + wx * 64) * 64);
#pragma unroll
    for (int u = 0; u < 11; ++u) {
      int i = u * 512 + t;
      if (u < 10 || i < 5280) {
        int r = i / 528, cc = i - r * 528;
        rg[u] = base[(size_t)r * (PW_ * 8) + cc];  // row stride = PW_*128 B = PW_*8 f16x8
      }
    }
  };

  issue(pid);  // tile for j=0

  const char* sInB = (const char*)sIn;
  const char* sWB = (const char*)sW;

#pragma unroll 1
  for (int j = 0; j < 5; ++j) {
    const int tt = pid + 128 * j;

    // ds_write staged tile (sIn f16x8-linear == staging index)
#pragma unroll
    for (int u = 0; u < 11; ++u) {
      int i = u * 512 + t;
      if (u < 10 || i < 5280) ((f16x8*)sIn)[i] = rg[u];
    }
    __syncthreads();

    if (j < 4) issue(pid + 128 * (j + 1));  // T14: next tile in flight over compute

    f32x4 acc1[4][2], acc2[4][2];
#pragma unroll
    for (int pa = 0; pa < 4; ++pa)
#pragma unroll
      for (int ob = 0; ob < 2; ++ob) {
        acc1[pa][ob] = (f32x4){0.f, 0.f, 0.f, 0.f};
        acc2[pa][ob] = (f32x4){0.f, 0.f, 0.f, 0.f};
      }

#pragma unroll
    for (int ky = 0; ky < 3; ++ky) {
#pragma unroll
      for (int kx = 0; kx < 3; ++kx) {
        const int tap = ky * 3 + kx;
#pragma unroll
        for (int kw = 0; kw < 2; ++kw) {
          f16x8 a[4], b1[2], b2[2];
#pragma unroll
          for (int pa = 0; pa < 4; ++pa)
            a[pa] = *(const f16x8*)(sInB + ((wv + ky) * 8448 + (pa * 16 + lr + kx) * 128 + c2a[kx][kw]));
#pragma unroll
          for (int ob = 0; ob < 2; ++ob) {
            b1[ob] = *(const f16x8*)(sWB + (tap * 4096 + (ob * 16 + lr) * 128 + c2b[kw]));
            b2[ob] = *(const f16x8*)(sWB + (36864 + tap * 4096 + (ob * 16 + lr) * 128 + c2b[kw]));
          }
#pragma unroll
          for (int pa = 0; pa < 4; ++pa)
#pragma unroll
            for (int ob = 0; ob < 2; ++ob) {
              acc1[pa][ob] = __builtin_amdgcn_mfma_f32_16x16x32_f16(a[pa], b1[ob], acc1[pa][ob], 0, 0, 0);
              acc2[pa][ob] = __builtin_amdgcn_mfma_f32_16x16x32_f16(a[pa], b2[ob], acc2[pa][ob], 0, 0, 0);
            }
        }
      }
    }

    // epilogue: bias + tanh(3x), direct stores (identity channel order)
    {
      int img = tt >> 6, hy = (tt >> 2) & 15, wx = tt & 3;
      size_t rowbase = ((size_t)(img * H_ + hy * 8 + wv) * W_ + wx * 64) * 64 + och * 32 + lr;
#pragma unroll
      for (int pa = 0; pa < 4; ++pa)
#pragma unroll
        for (int ob = 0; ob < 2; ++ob)
#pragma unroll
          for (int r = 0; r < 4; ++r) {
            int px = pa * 16 + hi * 4 + r;
            size_t o = rowbase + (size_t)px * 64 + ob * 16;
            float u1 = acc1[pa][ob][r] + bv1[ob];
            u1 = fminf(fmaxf(u1, -8.f), 8.f);
            float e1 = __builtin_exp2f(u1 * -8.656170245f);
            n1[o] = (_Float16)((1.f - e1) * __builtin_amdgcn_rcpf(1.f + e1));
            float u2 = acc2[pa][ob][r] + bv2[ob];
            u2 = fminf(fmaxf(u2, -8.f), 8.f);
            float e2 = __builtin_exp2f(u2 * -8.656170245f);
            n2[o] = (_Float16)((1.f - e2) * __builtin_amdgcn_rcpf(1.f + e2));
          }
    }
    __syncthreads();  // all waves done reading sIn before next ds_write
  }
}

// ---------------- gram + antisym + sigmoid + eye + row-normalize --------------
// 8 lanes cooperate per pixel: lane octet j owns channels 8j..8j+7.
__global__ __launch_bounds__(256)
void pairwise_kernel(const _Float16* __restrict__ n1, const _Float16* __restrict__ n2,
                     void* __restrict__ out, const int* __restrict__ flag) {
  int tid = blockIdx.x * 256 + threadIdx.x;
  int gp = tid >> 3;               // pixel id 0 .. B*HW-1
  int j = tid & 7;                 // channel octet
  int b = gp >> 15, px = gp & (HW_ - 1);
  const _Float16* p1 = n1 + ((size_t)(b * M_) * HW_ + px) * 64 + j * 8;
  const _Float16* p2 = n2 + ((size_t)(b * M_) * HW_ + px) * 64 + j * 8;

  f16x8 A[M_], Bv[M_];
#pragma unroll
  for (int m = 0; m < M_; ++m) {
    A[m]  = *(const f16x8*)(p1 + (size_t)m * PLANE_);
    Bv[m] = *(const f16x8*)(p2 + (size_t)m * PLANE_);
  }

  float s[M_][M_];
#pragma unroll
  for (int m = 0; m < M_; ++m)
#pragma unroll
    for (int n = 0; n < M_; ++n) s[m][n] = 0.f;

#pragma unroll
  for (int jj = 0; jj < 8; ++jj)
#pragma unroll
    for (int m = 0; m < M_; ++m)
#pragma unroll
      for (int n = 0; n < M_; ++n)
        s[m][n] += (float)A[m][jj] * (float)Bv[n][jj];

#pragma unroll
  for (int m = 0; m < M_; ++m)
#pragma unroll
    for (int n = 0; n < M_; ++n) {
      s[m][n] += __shfl_xor(s[m][n], 1);
      s[m][n] += __shfl_xor(s[m][n], 2);
      s[m][n] += __shfl_xor(s[m][n], 4);
    }

  float adj[M_][M_], rs[M_];
#pragma unroll
  for (int m = 0; m < M_; ++m) {
    float r = 0.f;
#pragma unroll
    for (int n = 0; n < M_; ++n) {
      float a = s[m][n] - s[n][m];
      float e = __builtin_exp2f(a * -4.328085123f);  // exp(-3a)
      float v = __builtin_amdgcn_rcpf(1.f + e);
      if (m == n) v += 1.f;
      adj[m][n] = v;
      r += v;
    }
    rs[m] = r;
  }

  const bool isb = flag[0] != 0;
  for (int k = j; k < 25; k += 8) {
    int m = k / 5, n = k - m * 5;
    float v = adj[m][n] * __builtin_amdgcn_rcpf(rs[m]);
    size_t o = ((size_t)((b * M_ + m) * M_ + n)) * HW_ + px;
    if (isb) ((__hip_bfloat16*)out)[o] = __float2bfloat16(v);
    else     ((float*)out)[o] = v;
  }
}

// ---------------- launch ----------------
extern "C" void kernel_launch(void* const* d_in, const int* in_sizes, int n_in,
                              void* d_out, int out_size, void* d_ws, size_t ws_size,
                              hipStream_t stream) {
  const void* pts = d_in[0];
  const void* W1  = d_in[1];
  const void* b1  = d_in[2];
  const void* W2  = d_in[3];
  const void* b2  = d_in[4];

  char* ws = (char*)d_ws;
  int* flag = (int*)ws;
  _Float16* xin = (_Float16*)(ws + OFF_XIN);
  _Float16* wl1 = (_Float16*)(ws + OFF_WL1);
  _Float16* wl2 = (_Float16*)(ws + OFF_WL2);
  _Float16* n1  = (_Float16*)(ws + OFF_N1);
  _Float16* n2  = (_Float16*)(ws + OFF_N2);

  sniff_kernel<<<dim3(1), dim3(64), 0, stream>>>((const unsigned short*)pts, flag);
  border_zero<<<dim3((NIMG_ * 772 + 255) / 256), dim3(256), 0, stream>>>(xin);
  prep_kernel<<<dim3(4, H_, NIMG_), dim3(256), 0, stream>>>(pts, xin, flag);
  wprep_kernel<<<dim3(144, 2), dim3(256), 0, stream>>>(W1, W2, wl1, wl2, flag);
  conv_fused<<<dim3(256), dim3(512), 0, stream>>>(xin, wl1, wl2, b1, b2, flag, n1, n2);
  pairwise_kernel<<<dim3(B_ * HW_ * 8 / 256), dim3(256), 0, stream>>>(n1, n2, d_out, flag);
}